// Round 1
// baseline (566.780 us; speedup 1.0000x reference)
//
#include <hip/hip_runtime.h>

// Problem constants (fixed by the reference)
#define NN   100000   // nodes
#define NE   3200000  // edges
#define DIMK 256      // feature dim
#define NC   32       // classes
#define NG   64       // graphs

// Workspace layout (bytes). Total ~59.7 MB.
static constexpr size_t OFF_A     = 0;           // [NN][NG] f32 = 25,600,000
static constexpr size_t OFF_DEG   = 25600000;    // [NN] f32 (deg, then dinv in place)
static constexpr size_t OFF_START = 26000000;    // [NG+1] int  (graph start offsets)
static constexpr size_t OFF_FLAG  = 26000320;    // int (1 = indices are int64)
static constexpr size_t OFF_S     = 26000384;    // [NG][DIMK] f32 = 65,536
static constexpr size_t OFF_PART  = 26065920;    // [nblk][NG*DIMK] f32

#define NBLK_GEMM 512

__device__ __forceinline__ int idx_at(const void* p, long i, bool i64) {
    return i64 ? (int)((const long long*)p)[i] : ((const int*)p)[i];
}

// Detect int64 vs int32 index arrays: for int64 (LE), the high 32-bit words of
// the first edge entries are all zero. For genuine int32 random indices in
// [0,100000), odd words are ~never all zero (P ≈ 1e-30).
__global__ void k_detect(const int* __restrict__ ei_raw, int* __restrict__ flag) {
    int z = (ei_raw[1] == 0) + (ei_raw[3] == 0) + (ei_raw[5] == 0) +
            (ei_raw[7] == 0) + (ei_raw[9] == 0) + (ei_raw[11] == 0);
    *flag = (z == 6) ? 1 : 0;
}

__global__ void k_init_deg(float* __restrict__ deg) {
    int i = blockIdx.x * 256 + threadIdx.x;
    if (i < NN) deg[i] = 1.0f;  // self-loop
}

// deg histogram at dst + graph boundary offsets from sorted batch
__global__ void k_deg_start(const void* __restrict__ ei, const void* __restrict__ batch,
                            float* __restrict__ deg, int* __restrict__ start,
                            const int* __restrict__ flag) {
    const bool i64 = (*flag) != 0;
    int e = blockIdx.x * 256 + threadIdx.x;
    if (e < NE) {
        int d = idx_at(ei, (long)NE + e, i64);
        atomicAdd(&deg[d], 1.0f);
    }
    if (e < NN) {
        int bi = idx_at(batch, e, i64);
        int bp = (e == 0) ? -1 : idx_at(batch, e - 1, i64);
        for (int g = bp + 1; g <= bi; ++g) start[g] = e;
        if (e == NN - 1) {
            for (int g = bi + 1; g <= NG; ++g) start[g] = NN;
        }
    }
}

__global__ void k_dinv(float* __restrict__ deg) {
    int i = blockIdx.x * 256 + threadIdx.x;
    if (i < NN) deg[i] = 1.0f / sqrtf(deg[i]);  // deg >= 1 always (self-loop)
}

// A[src][batch[dst]] += dinv[dst]
__global__ void k_scatter(const void* __restrict__ ei, const void* __restrict__ batch,
                          const float* __restrict__ dinv, float* __restrict__ A,
                          const int* __restrict__ flag) {
    const bool i64 = (*flag) != 0;
    int e = blockIdx.x * 256 + threadIdx.x;
    if (e >= NE) return;
    int s = idx_at(ei, e, i64);
    int d = idx_at(ei, (long)NE + e, i64);
    int g = idx_at(batch, d, i64);
    atomicAdd(&A[(size_t)s * NG + g], dinv[d]);
}

// S_partial[b] = sum over this block's node range of P[j][:] (outer) x[j][:]
// P[j][g] = dinv[j]*A[j][g] + dinv[j]^2 * (batch[j]==g)
#define JB 32
__global__ __launch_bounds__(256) void k_sgemm(
    const float* __restrict__ x, const float* __restrict__ A,
    const float* __restrict__ dinv, const void* __restrict__ batch,
    float* __restrict__ part, const int* __restrict__ flag, int per) {
    __shared__ float  xs[JB][DIMK];     // 32 KB
    __shared__ float4 Ps[JB][NG / 4];   // 8 KB
    const bool i64 = (*flag) != 0;
    const int tid = threadIdx.x;
    const int gi = tid >> 5;   // 0..7  -> graphs gi*8 .. gi*8+7
    const int di = tid & 31;   // d = di + 32*k, k=0..7
    const int b = blockIdx.x;
    const int j0 = b * per;
    const int j1 = min(j0 + per, NN);

    float acc[8][8];
#pragma unroll
    for (int g = 0; g < 8; ++g)
#pragma unroll
        for (int k = 0; k < 8; ++k) acc[g][k] = 0.0f;

    const float4* x4 = (const float4*)x;
    const float4* A4 = (const float4*)A;

    for (int c0 = j0; c0 < j1; c0 += JB) {
        // stage x chunk (zero OOB rows to keep FMA contributions exactly 0)
#pragma unroll
        for (int t = tid; t < JB * (DIMK / 4); t += 256) {
            int jj = t >> 6;           // DIMK/4 = 64 float4 per row
            int d4 = t & 63;
            int j = c0 + jj;
            float4 v = make_float4(0.f, 0.f, 0.f, 0.f);
            if (j < j1) v = x4[(size_t)j * (DIMK / 4) + d4];
            ((float4*)xs[jj])[d4] = v;
        }
        // stage P chunk (fused dinv scale + self-loop term)
#pragma unroll
        for (int t = tid; t < JB * (NG / 4); t += 256) {
            int jj = t >> 4;           // NG/4 = 16 float4 per row
            int gq = t & 15;
            int j = c0 + jj;
            float4 v = make_float4(0.f, 0.f, 0.f, 0.f);
            if (j < j1) {
                float dv = dinv[j];
                int bg = idx_at(batch, j, i64);
                float4 a = A4[(size_t)j * (NG / 4) + gq];
                v.x = dv * a.x; v.y = dv * a.y; v.z = dv * a.z; v.w = dv * a.w;
                int g0 = gq * 4;
                if (bg >= g0 && bg < g0 + 4) {
                    float d2 = dv * dv;
                    if      (bg == g0)     v.x += d2;
                    else if (bg == g0 + 1) v.y += d2;
                    else if (bg == g0 + 2) v.z += d2;
                    else                   v.w += d2;
                }
            }
            Ps[jj][gq] = v;
        }
        __syncthreads();

        const int jmax = min(JB, j1 - c0);
#pragma unroll 2
        for (int jj = 0; jj < jmax; ++jj) {
            float4 p0 = Ps[jj][gi * 2 + 0];
            float4 p1 = Ps[jj][gi * 2 + 1];
            float xv[8];
#pragma unroll
            for (int k = 0; k < 8; ++k) xv[k] = xs[jj][di + 32 * k];  // bank-free (stride 32)
            float pg[8] = {p0.x, p0.y, p0.z, p0.w, p1.x, p1.y, p1.z, p1.w};
#pragma unroll
            for (int g = 0; g < 8; ++g)
#pragma unroll
                for (int k = 0; k < 8; ++k)
                    acc[g][k] = fmaf(pg[g], xv[k], acc[g][k]);
        }
        __syncthreads();
    }

    // write block partial (all blocks write, even empty ranges -> zeros)
    float* p = part + (size_t)b * (NG * DIMK);
#pragma unroll
    for (int g = 0; g < 8; ++g) {
        int gg = gi * 8 + g;
#pragma unroll
        for (int k = 0; k < 8; ++k)
            p[gg * DIMK + k * 32 + di] = acc[g][k];
    }
}

__global__ void k_reduce(const float4* __restrict__ part, float4* __restrict__ S, int nblk) {
    int i = blockIdx.x * 256 + threadIdx.x;  // 0..4095 (NG*DIMK/4)
    float4 s = make_float4(0.f, 0.f, 0.f, 0.f);
    for (int b = 0; b < nblk; ++b) {
        float4 v = part[(size_t)b * (NG * DIMK / 4) + i];
        s.x += v.x; s.y += v.y; s.z += v.z; s.w += v.w;
    }
    S[i] = s;
}

__global__ void k_final(const float* __restrict__ S, const float* __restrict__ W,
                        const float* __restrict__ bias, const int* __restrict__ start,
                        float* __restrict__ out) {
    int idx = blockIdx.x * 256 + threadIdx.x;  // 0..2047
    int g = idx >> 5;
    int c = idx & 31;
    float sum = 0.f;
#pragma unroll 8
    for (int d = 0; d < DIMK; ++d)
        sum = fmaf(S[g * DIMK + d], W[d * NC + c], sum);
    float cn = (float)max(start[g + 1] - start[g], 1);
    out[idx] = sum / cn + bias[c];
}

extern "C" void kernel_launch(void* const* d_in, const int* in_sizes, int n_in,
                              void* d_out, int out_size, void* d_ws, size_t ws_size,
                              hipStream_t stream) {
    const float* x    = (const float*)d_in[0];
    const float* W    = (const float*)d_in[1];
    const float* bias = (const float*)d_in[2];
    const void*  ei   = d_in[3];
    const void*  batch= d_in[4];
    float* out = (float*)d_out;

    char* ws = (char*)d_ws;
    float* A    = (float*)(ws + OFF_A);
    float* deg  = (float*)(ws + OFF_DEG);   // becomes dinv after k_dinv
    int*   start= (int*)(ws + OFF_START);
    int*   flag = (int*)(ws + OFF_FLAG);
    float* S    = (float*)(ws + OFF_S);
    float* part = (float*)(ws + OFF_PART);

    // shrink partial-block count if workspace is tight
    int nblk = NBLK_GEMM;
    if (ws_size < OFF_PART + (size_t)nblk * NG * DIMK * sizeof(float)) nblk = 128;
    const int per = (NN + nblk - 1) / nblk;

    k_detect<<<1, 1, 0, stream>>>((const int*)ei, flag);
    hipMemsetAsync(A, 0, (size_t)NN * NG * sizeof(float), stream);
    k_init_deg<<<(NN + 255) / 256, 256, 0, stream>>>(deg);
    k_deg_start<<<NE / 256, 256, 0, stream>>>(ei, batch, deg, start, flag);
    k_dinv<<<(NN + 255) / 256, 256, 0, stream>>>(deg);
    k_scatter<<<NE / 256, 256, 0, stream>>>(ei, batch, deg, A, flag);
    k_sgemm<<<nblk, 256, 0, stream>>>(x, A, deg, batch, part, flag, per);
    k_reduce<<<16, 256, 0, stream>>>((const float4*)part, (float4*)S, nblk);
    k_final<<<8, 256, 0, stream>>>(S, W, bias, start, out);
}

// Round 2
// 482.809 us; speedup vs baseline: 1.1739x; 1.1739x over previous
//
#include <hip/hip_runtime.h>

// Problem constants (fixed by the reference)
#define NN    100000   // nodes
#define NE    3200000  // edges
#define DIMK  256      // feature dim
#define NC    32       // classes
#define NG    64       // graphs

#define ROWS  128      // nodes per src-bucket (A-chunk rows)
#define NBUCK 782      // ceil(NN / ROWS)
#define NB1   512      // edge-chunk blocks for bucketing (NE/NB1 = 6250 exact)
#define EPB   6250     // edges per bucketing block
#define NSCAN 391      // scan chunks: NBUCK*NB1 / 1024 = 400384/1024 = 391 exact

// Workspace layout (bytes).
// records (25.6 MB) overlays deg-partials (12.8 MB): deg parts are dead before
// k_place writes records. Peak use <= 80.5 MB (782-tier) with fallbacks.
static constexpr size_t OFF_REC   = 0;            // [NE] uint2 = 25,600,000  (first 12.8MB doubles as deg parts)
static constexpr size_t OFF_DINV  = 25600000;     // [NN] f32
static constexpr size_t OFF_CNT   = 26000000;     // [NBUCK*NB1] int = 1,601,536
static constexpr size_t OFF_EXC   = 27601536;     // [NBUCK*NB1] int
static constexpr size_t OFF_BSUM  = 29203072;     // [NSCAN] int (pad 2048)
static constexpr size_t OFF_TOPS  = 29205120;     // [NSCAN] int (pad 2048)
static constexpr size_t OFF_START = 29207168;     // [NG+1] int (pad 512)
static constexpr size_t OFF_FLAG  = 29207680;     // int (pad 128)
static constexpr size_t OFF_S     = 29207808;     // [NG*DIMK] f32 = 65,536
static constexpr size_t OFF_PART  = 29273344;     // [nblk][NG*DIMK] f32

__device__ __forceinline__ int idx_at(const void* p, long i, bool i64) {
    return i64 ? (int)((const long long*)p)[i] : ((const int*)p)[i];
}

// int64 vs int32 detection: high words of first int64 entries are all zero.
__global__ void k_detect(const int* __restrict__ ei_raw, int* __restrict__ flag) {
    int z = (ei_raw[1] == 0) + (ei_raw[3] == 0) + (ei_raw[5] == 0) +
            (ei_raw[7] == 0) + (ei_raw[9] == 0) + (ei_raw[11] == 0);
    *flag = (z == 6) ? 1 : 0;
}

// LDS-privatized degree histogram (u8 counters; max degree ~64 << 255).
// Block b: half h=b>>7 (node range [h*50000, h*50000+50000)), slice sl=b&127
// (edges [sl*25000, +25000)). Writes per-block u8 partial histogram.
__global__ __launch_bounds__(256) void k_deg_hist(const void* __restrict__ ei,
        unsigned int* __restrict__ parts, const int* __restrict__ flag) {
    __shared__ unsigned int h[12500];   // 50 KB: 50000 u8 counters
    const bool i64 = (*flag) != 0;
    const int b = blockIdx.x;
    const int hh = b >> 7;
    const int sl = b & 127;
    const int lo = hh * 50000, hi = lo + 50000;
    for (int t = threadIdx.x; t < 12500; t += 256) h[t] = 0u;
    __syncthreads();
    const int e0 = sl * 25000;
    for (int e = e0 + threadIdx.x; e < e0 + 25000; e += 256) {
        int d = idx_at(ei, (long)NE + e, i64);
        if (d >= lo && d < hi) {
            int r = d - lo;
            atomicAdd(&h[r >> 2], 1u << ((r & 3) * 8));
        }
    }
    __syncthreads();
    for (int t = threadIdx.x; t < 12500; t += 256)
        parts[(size_t)b * 12500 + t] = h[t];
}

// deg[i] = 1 (self-loop) + sum of byte counters; emit dinv = 1/sqrt(deg).
__global__ void k_deg_reduce(const unsigned int* __restrict__ parts,
                             float* __restrict__ dinv) {
    int i = blockIdx.x * 256 + threadIdx.x;   // word index, 0..24999
    if (i >= 25000) return;
    int h = (i >= 12500) ? 1 : 0;
    int w = i - h * 12500;
    int c0 = 0, c1 = 0, c2 = 0, c3 = 0;
    const unsigned int* base = parts + (size_t)(h * 128) * 12500 + w;
    for (int s = 0; s < 128; ++s) {
        unsigned int v = base[(size_t)s * 12500];
        c0 += v & 255u; c1 += (v >> 8) & 255u; c2 += (v >> 16) & 255u; c3 += v >> 24;
    }
    int node = h * 50000 + w * 4;
    dinv[node]     = 1.0f / sqrtf((float)(1 + c0));
    dinv[node + 1] = 1.0f / sqrtf((float)(1 + c1));
    dinv[node + 2] = 1.0f / sqrtf((float)(1 + c2));
    dinv[node + 3] = 1.0f / sqrtf((float)(1 + c3));
}

// Graph boundary offsets from sorted batch.
__global__ void k_start(const void* __restrict__ batch, int* __restrict__ start,
                        const int* __restrict__ flag) {
    const bool i64 = (*flag) != 0;
    int i = blockIdx.x * 256 + threadIdx.x;
    if (i >= NN) return;
    int bi = idx_at(batch, i, i64);
    int bp = (i == 0) ? -1 : idx_at(batch, i - 1, i64);
    for (int g = bp + 1; g <= bi; ++g) start[g] = i;
    if (i == NN - 1)
        for (int g = bi + 1; g <= NG; ++g) start[g] = NN;
}

// Per-(bucket, block) edge counts via LDS counters. cnt_part[bucket][block].
__global__ __launch_bounds__(256) void k_bucket_count(const void* __restrict__ ei,
        int* __restrict__ cnt_part, const int* __restrict__ flag) {
    __shared__ unsigned int lc[NBUCK];
    const bool i64 = (*flag) != 0;
    const int k = blockIdx.x;
    for (int t = threadIdx.x; t < NBUCK; t += 256) lc[t] = 0u;
    __syncthreads();
    const int e0 = k * EPB;
    for (int e = e0 + threadIdx.x; e < e0 + EPB; e += 256) {
        int s = idx_at(ei, e, i64);
        atomicAdd(&lc[s >> 7], 1u);
    }
    __syncthreads();
    for (int t = threadIdx.x; t < NBUCK; t += 256)
        cnt_part[t * NB1 + k] = (int)lc[t];
}

// Exclusive scan, stage 1: per-1024-chunk scan + chunk sums.
__global__ void k_scan_partial(const int* __restrict__ cnt, int* __restrict__ exc,
                               int* __restrict__ bsum) {
    __shared__ int s[1024];
    int i = blockIdx.x * 1024 + threadIdx.x;
    int v = cnt[i];
    s[threadIdx.x] = v;
    __syncthreads();
    for (int off = 1; off < 1024; off <<= 1) {
        int t = (threadIdx.x >= off) ? s[threadIdx.x - off] : 0;
        __syncthreads();
        s[threadIdx.x] += t;
        __syncthreads();
    }
    exc[i] = s[threadIdx.x] - v;
    if (threadIdx.x == 1023) bsum[blockIdx.x] = s[1023];
}

// Exclusive scan, stage 2: scan the 391 chunk sums (trivial).
__global__ void k_scan_tops(const int* __restrict__ bsum, int* __restrict__ tops) {
    if (threadIdx.x == 0 && blockIdx.x == 0) {
        int run = 0;
        for (int c = 0; c < NSCAN; ++c) { tops[c] = run; run += bsum[c]; }
    }
}

// Place edge records into bucket-contiguous order. Record = {Ach index, dinv[dst]}.
__global__ __launch_bounds__(256) void k_place(const void* __restrict__ ei,
        const void* __restrict__ batch, const float* __restrict__ dinv,
        const int* __restrict__ exc, const int* __restrict__ tops,
        uint2* __restrict__ rec, const int* __restrict__ flag) {
    __shared__ unsigned int lc[NBUCK];
    const bool i64 = (*flag) != 0;
    const int k = blockIdx.x;
    for (int t = threadIdx.x; t < NBUCK; t += 256) lc[t] = 0u;
    __syncthreads();
    const int e0 = k * EPB;
    for (int e = e0 + threadIdx.x; e < e0 + EPB; e += 256) {
        int s = idx_at(ei, e, i64);
        int d = idx_at(ei, (long)NE + e, i64);
        int g = idx_at(batch, d, i64);
        float val = dinv[d];
        int b = s >> 7;
        unsigned int r = atomicAdd(&lc[b], 1u);
        int ii = b * NB1 + k;
        int pos = exc[ii] + tops[ii >> 10] + (int)r;
        rec[pos] = make_uint2((unsigned)((s & 127) * 64 + g), __float_as_uint(val));
    }
}

// Fused: per src-bucket, build A'-chunk in LDS (records via LDS atomics; row jl
// initialized with self-loop dinv[j] at col batch[j]), then accumulate
// S_part[g][d] += A'[jl][g] * (dinv[j] * x[j][d]) via register outer products.
__global__ __launch_bounds__(256) void k_fused(
        const float* __restrict__ x, const float* __restrict__ dinv,
        const void* __restrict__ batch, const uint2* __restrict__ rec,
        const int* __restrict__ exc, const int* __restrict__ tops,
        float* __restrict__ part, const int* __restrict__ flag) {
    __shared__ __align__(16) float Ach[ROWS * 64];   // 32 KB
    __shared__ __align__(16) float xs[16][DIMK];     // 16 KB
    const bool i64 = (*flag) != 0;
    const int tid = threadIdx.x;
    const int gi = tid >> 5;    // graph group 0..7
    const int di = tid & 31;    // feature lane

    float acc[8][8];
#pragma unroll
    for (int g = 0; g < 8; ++g)
#pragma unroll
        for (int k = 0; k < 8; ++k) acc[g][k] = 0.0f;

    for (int bkt = blockIdx.x; bkt < NBUCK; bkt += gridDim.x) {
        const int j0 = bkt * ROWS;
        for (int t = tid; t < ROWS * 64; t += 256) Ach[t] = 0.0f;
        __syncthreads();
        if (tid < ROWS) {
            int j = j0 + tid;
            if (j < NN) Ach[tid * 64 + idx_at(batch, j, i64)] = dinv[j];
        }
        __syncthreads();
        const int ia = bkt * NB1;
        const int rbeg = exc[ia] + tops[ia >> 10];
        int rend;
        if (bkt + 1 < NBUCK) {
            int ib = ia + NB1;
            rend = exc[ib] + tops[ib >> 10];
        } else rend = NE;
        for (int r = rbeg + tid; r < rend; r += 256) {
            uint2 q = rec[r];
            atomicAdd(&Ach[q.x], __uint_as_float(q.y));
        }
        __syncthreads();

        for (int c0 = 0; c0 < ROWS; c0 += 16) {
            // stage 16 x-rows scaled by dinv (zero pad rows -> contribute 0)
            for (int t = tid; t < 16 * 64; t += 256) {
                int jj = t >> 6, d4 = t & 63;
                int j = j0 + c0 + jj;
                float4 v = make_float4(0.f, 0.f, 0.f, 0.f);
                if (j < NN) {
                    float dv = dinv[j];
                    float4 u = ((const float4*)x)[(size_t)j * 64 + d4];
                    v.x = dv * u.x; v.y = dv * u.y; v.z = dv * u.z; v.w = dv * u.w;
                }
                ((float4*)xs[jj])[d4] = v;
            }
            __syncthreads();
#pragma unroll
            for (int jj = 0; jj < 16; ++jj) {
                const float* arow = &Ach[(c0 + jj) * 64 + gi * 8];
                float4 p0 = *(const float4*)arow;       // broadcast per half-wave
                float4 p1 = *(const float4*)(arow + 4);
                float xv[8];
#pragma unroll
                for (int k = 0; k < 8; ++k) xv[k] = xs[jj][di + 32 * k];  // bank-free
                float pg[8] = {p0.x, p0.y, p0.z, p0.w, p1.x, p1.y, p1.z, p1.w};
#pragma unroll
                for (int g = 0; g < 8; ++g)
#pragma unroll
                    for (int k = 0; k < 8; ++k)
                        acc[g][k] = fmaf(pg[g], xv[k], acc[g][k]);
            }
            __syncthreads();
        }
    }

    float* p = part + (size_t)blockIdx.x * (NG * DIMK);
#pragma unroll
    for (int g = 0; g < 8; ++g) {
        int gg = gi * 8 + g;
#pragma unroll
        for (int k = 0; k < 8; ++k)
            p[gg * DIMK + k * 32 + di] = acc[g][k];
    }
}

__global__ void k_reduce_S(const float* __restrict__ part, float* __restrict__ S,
                           int nblk) {
    int i = blockIdx.x * 256 + threadIdx.x;   // 0..16383
    float s = 0.f;
    for (int b = 0; b < nblk; ++b) s += part[(size_t)b * (NG * DIMK) + i];
    S[i] = s;
}

__global__ void k_final(const float* __restrict__ S, const float* __restrict__ W,
                        const float* __restrict__ bias, const int* __restrict__ start,
                        float* __restrict__ out) {
    int idx = blockIdx.x * 256 + threadIdx.x;  // 0..2047
    int g = idx >> 5;
    int c = idx & 31;
    float sum = 0.f;
#pragma unroll 8
    for (int d = 0; d < DIMK; ++d)
        sum = fmaf(S[g * DIMK + d], W[d * NC + c], sum);
    float cn = (float)max(start[g + 1] - start[g], 1);
    out[idx] = sum / cn + bias[c];
}

extern "C" void kernel_launch(void* const* d_in, const int* in_sizes, int n_in,
                              void* d_out, int out_size, void* d_ws, size_t ws_size,
                              hipStream_t stream) {
    const float* x    = (const float*)d_in[0];
    const float* W    = (const float*)d_in[1];
    const float* bias = (const float*)d_in[2];
    const void*  ei   = d_in[3];
    const void*  batch= d_in[4];
    float* out = (float*)d_out;

    char* ws = (char*)d_ws;
    uint2* rec   = (uint2*)(ws + OFF_REC);
    unsigned int* degp = (unsigned int*)(ws + OFF_REC);  // overlay (dead before rec)
    float* dinv  = (float*)(ws + OFF_DINV);
    int*   cntp  = (int*)(ws + OFF_CNT);
    int*   exc   = (int*)(ws + OFF_EXC);
    int*   bsum  = (int*)(ws + OFF_BSUM);
    int*   tops  = (int*)(ws + OFF_TOPS);
    int*   start = (int*)(ws + OFF_START);
    int*   flag  = (int*)(ws + OFF_FLAG);
    float* S     = (float*)(ws + OFF_S);
    float* part  = (float*)(ws + OFF_PART);

    int nblk = 64;
    if      (ws_size >= OFF_PART + 782ull * NG * DIMK * 4) nblk = 782;
    else if (ws_size >= OFF_PART + 256ull * NG * DIMK * 4) nblk = 256;
    else if (ws_size >= OFF_PART + 128ull * NG * DIMK * 4) nblk = 128;

    k_detect      <<<1, 1, 0, stream>>>((const int*)ei, flag);
    k_deg_hist    <<<256, 256, 0, stream>>>(ei, degp, flag);
    k_deg_reduce  <<<98, 256, 0, stream>>>(degp, dinv);
    k_start       <<<391, 256, 0, stream>>>(batch, start, flag);
    k_bucket_count<<<NB1, 256, 0, stream>>>(ei, cntp, flag);
    k_scan_partial<<<NSCAN, 1024, 0, stream>>>(cntp, exc, bsum);
    k_scan_tops   <<<1, 64, 0, stream>>>(bsum, tops);
    k_place       <<<NB1, 256, 0, stream>>>(ei, batch, dinv, exc, tops, rec, flag);
    k_fused       <<<nblk, 256, 0, stream>>>(x, dinv, batch, rec, exc, tops, part, flag);
    k_reduce_S    <<<64, 256, 0, stream>>>(part, S, nblk);
    k_final       <<<8, 256, 0, stream>>>(S, W, bias, start, out);
}

// Round 3
// 247.556 us; speedup vs baseline: 2.2895x; 1.9503x over previous
//
#include <hip/hip_runtime.h>

// Problem constants (fixed by the reference)
#define NN    100000   // nodes
#define NE    3200000  // edges
#define DIMK  256      // feature dim
#define NC    32       // classes
#define NG    64       // graphs

#define ROWS  128      // nodes per src-bucket (A-chunk rows)
#define NBUCK 782      // ceil(NN / ROWS)
#define NB1   512      // edge-chunk blocks for bucketing (NE/NB1 = 6250 exact)
#define EPB   6250     // edges per bucketing block
#define NSCAN 391      // NBUCK*NB1/1024 = 391 exact
#define NSL   16       // reduce slices

// Workspace layout (bytes). Records (12.8 MB) overlay deg partials (12.8 MB):
// deg partials are dead before k_place writes records. Total 43.6 MB.
static constexpr size_t OFF_REC    = 0;           // [NE] u32 = 12,800,000 (also 256*12500 u32 deg parts)
static constexpr size_t OFF_DEGARR = 12800000;    // [NN] u32
static constexpr size_t OFF_DINV   = 13200000;    // [NN] f32
static constexpr size_t OFF_CNT    = 13600000;    // [NBUCK*NB1] int = 1,601,536
static constexpr size_t OFF_EXC    = 15201536;    // [NBUCK*NB1] int
static constexpr size_t OFF_BSUM   = 16803072;    // [NSCAN] int (pad 2048)
static constexpr size_t OFF_TOPS   = 16805120;    // [NSCAN] int (pad 2048)
static constexpr size_t OFF_START  = 16807168;    // [NG+1] int (pad 512)
static constexpr size_t OFF_FLAG   = 16807680;    // int (pad 128)
static constexpr size_t OFF_S      = 16807808;    // [NG*DIMK] f32 = 65,536
static constexpr size_t OFF_P2     = 16873344;    // [NSL][NG*DIMK] f32 = 1,048,576
static constexpr size_t OFF_PART   = 17921920;    // [nblk][NG*DIMK] f32

__device__ __forceinline__ int idx_at(const void* p, long i, bool i64) {
    return i64 ? (int)((const long long*)p)[i] : ((const int*)p)[i];
}

// int64 vs int32 detection: high words of first int64 entries are all zero.
__global__ void k_detect(const int* __restrict__ ei_raw, int* __restrict__ flag) {
    int z = (ei_raw[1] == 0) + (ei_raw[3] == 0) + (ei_raw[5] == 0) +
            (ei_raw[7] == 0) + (ei_raw[9] == 0) + (ei_raw[11] == 0);
    *flag = (z == 6) ? 1 : 0;
}

// LDS-privatized degree histogram (u8 counters; max degree ~70 << 255).
// Block b: half hh=b>>7 (node range 50000), slice sl=b&127 (25000 edges).
__global__ __launch_bounds__(256) void k_deg_hist(const void* __restrict__ ei,
        unsigned int* __restrict__ parts, const int* __restrict__ flag) {
    __shared__ unsigned int h[12500];   // 50 KB: 50000 u8 counters
    const bool i64 = (*flag) != 0;
    const int b = blockIdx.x;
    const int hh = b >> 7;
    const int sl = b & 127;
    const int lo = hh * 50000, hi = lo + 50000;
    for (int t = threadIdx.x; t < 12500; t += 256) h[t] = 0u;
    __syncthreads();
    const int e0 = sl * 25000;
    for (int e = e0 + threadIdx.x; e < e0 + 25000; e += 256) {
        int d = idx_at(ei, (long)NE + e, i64);
        if (d >= lo && d < hi) {
            int r = d - lo;
            atomicAdd(&h[r >> 2], 1u << ((r & 3) * 8));
        }
    }
    __syncthreads();
    for (int t = threadIdx.x; t < 12500; t += 256)
        parts[(size_t)b * 12500 + t] = h[t];
}

// deg = 1 (self-loop) + byte-counter sum; emit u32 deg and f32 dinv.
__global__ void k_deg_reduce(const unsigned int* __restrict__ parts,
                             unsigned int* __restrict__ degarr,
                             float* __restrict__ dinv) {
    int i = blockIdx.x * 256 + threadIdx.x;   // word index, 0..24999
    if (i >= 25000) return;
    int h = (i >= 12500) ? 1 : 0;
    int w = i - h * 12500;
    int c0 = 0, c1 = 0, c2 = 0, c3 = 0;
    const unsigned int* base = parts + (size_t)(h * 128) * 12500 + w;
#pragma unroll 4
    for (int s = 0; s < 128; ++s) {
        unsigned int v = base[(size_t)s * 12500];
        c0 += v & 255u; c1 += (v >> 8) & 255u; c2 += (v >> 16) & 255u; c3 += v >> 24;
    }
    int node = h * 50000 + w * 4;
    degarr[node]     = 1u + c0;  dinv[node]     = 1.0f / sqrtf((float)(1 + c0));
    degarr[node + 1] = 1u + c1;  dinv[node + 1] = 1.0f / sqrtf((float)(1 + c1));
    degarr[node + 2] = 1u + c2;  dinv[node + 2] = 1.0f / sqrtf((float)(1 + c2));
    degarr[node + 3] = 1u + c3;  dinv[node + 3] = 1.0f / sqrtf((float)(1 + c3));
}

// Graph boundary offsets from sorted batch.
__global__ void k_start(const void* __restrict__ batch, int* __restrict__ start,
                        const int* __restrict__ flag) {
    const bool i64 = (*flag) != 0;
    int i = blockIdx.x * 256 + threadIdx.x;
    if (i >= NN) return;
    int bi = idx_at(batch, i, i64);
    int bp = (i == 0) ? -1 : idx_at(batch, i - 1, i64);
    for (int g = bp + 1; g <= bi; ++g) start[g] = i;
    if (i == NN - 1)
        for (int g = bi + 1; g <= NG; ++g) start[g] = NN;
}

// Per-(bucket, block) edge counts via LDS counters. cnt_part[bucket][block].
__global__ __launch_bounds__(256) void k_bucket_count(const void* __restrict__ ei,
        int* __restrict__ cnt_part, const int* __restrict__ flag) {
    __shared__ unsigned int lc[NBUCK];
    const bool i64 = (*flag) != 0;
    const int k = blockIdx.x;
    for (int t = threadIdx.x; t < NBUCK; t += 256) lc[t] = 0u;
    __syncthreads();
    const int e0 = k * EPB;
    for (int e = e0 + threadIdx.x; e < e0 + EPB; e += 256) {
        int s = idx_at(ei, e, i64);
        atomicAdd(&lc[s >> 7], 1u);
    }
    __syncthreads();
    for (int t = threadIdx.x; t < NBUCK; t += 256)
        cnt_part[t * NB1 + k] = (int)lc[t];
}

// Exclusive scan, stage 1: per-1024-chunk scan + chunk sums.
__global__ void k_scan_partial(const int* __restrict__ cnt, int* __restrict__ exc,
                               int* __restrict__ bsum) {
    __shared__ int s[1024];
    int i = blockIdx.x * 1024 + threadIdx.x;
    int v = cnt[i];
    s[threadIdx.x] = v;
    __syncthreads();
    for (int off = 1; off < 1024; off <<= 1) {
        int t = (threadIdx.x >= off) ? s[threadIdx.x - off] : 0;
        __syncthreads();
        s[threadIdx.x] += t;
        __syncthreads();
    }
    exc[i] = s[threadIdx.x] - v;
    if (threadIdx.x == 1023) bsum[blockIdx.x] = s[1023];
}

// Exclusive scan, stage 2: scan the 391 chunk sums (trivial).
__global__ void k_scan_tops(const int* __restrict__ bsum, int* __restrict__ tops) {
    if (threadIdx.x == 0 && blockIdx.x == 0) {
        int run = 0;
        for (int c = 0; c < NSCAN; ++c) { tops[c] = run; run += bsum[c]; }
    }
}

// Place 4-byte edge records: (deg[dst] << 13) | ((src&127)*64 + batch[dst]).
__global__ __launch_bounds__(256) void k_place(const void* __restrict__ ei,
        const void* __restrict__ batch, const unsigned int* __restrict__ degarr,
        const int* __restrict__ exc, const int* __restrict__ tops,
        unsigned int* __restrict__ rec, const int* __restrict__ flag) {
    __shared__ unsigned int lc[NBUCK];
    __shared__ int lbase[NBUCK];
    const bool i64 = (*flag) != 0;
    const int k = blockIdx.x;
    for (int t = threadIdx.x; t < NBUCK; t += 256) {
        lc[t] = 0u;
        int ii = t * NB1 + k;
        lbase[t] = exc[ii] + tops[ii >> 10];
    }
    __syncthreads();
    const int e0 = k * EPB;
    for (int e = e0 + threadIdx.x; e < e0 + EPB; e += 256) {
        int s = idx_at(ei, e, i64);
        int d = idx_at(ei, (long)NE + e, i64);
        int g = idx_at(batch, d, i64);
        unsigned int deg = min(degarr[d], 524287u);
        int b = s >> 7;
        unsigned int r = atomicAdd(&lc[b], 1u);
        rec[lbase[b] + (int)r] = (deg << 13) | (unsigned)((s & 127) * 64 + g);
    }
}

// Fused: per src-bucket, build A'-chunk in LDS (records via LDS atomics; row jl
// seeded with self-loop dinv[j] at col batch[j]), then accumulate
// S_part[g][d] += A'[jl][g] * (dinv[j] * x[j][d]) via register outer products.
__global__ __launch_bounds__(256) void k_fused(
        const float* __restrict__ x, const float* __restrict__ dinv,
        const void* __restrict__ batch, const unsigned int* __restrict__ rec,
        const int* __restrict__ exc, const int* __restrict__ tops,
        float* __restrict__ part, const int* __restrict__ flag) {
    __shared__ __align__(16) float Ach[ROWS * 64];   // 32 KB
    __shared__ __align__(16) float xs[16][DIMK];     // 16 KB
    const bool i64 = (*flag) != 0;
    const int tid = threadIdx.x;
    const int gi = tid >> 5;    // graph group 0..7
    const int di = tid & 31;    // feature lane

    float acc[8][8];
#pragma unroll
    for (int g = 0; g < 8; ++g)
#pragma unroll
        for (int k = 0; k < 8; ++k) acc[g][k] = 0.0f;

    for (int bkt = blockIdx.x; bkt < NBUCK; bkt += gridDim.x) {
        const int j0 = bkt * ROWS;
        for (int t = tid; t < ROWS * 64; t += 256) Ach[t] = 0.0f;
        __syncthreads();
        if (tid < ROWS) {
            int j = j0 + tid;
            if (j < NN) Ach[tid * 64 + idx_at(batch, j, i64)] = dinv[j];
        }
        __syncthreads();
        const int ia = bkt * NB1;
        const int rbeg = exc[ia] + tops[ia >> 10];
        int rend;
        if (bkt + 1 < NBUCK) {
            int ib = ia + NB1;
            rend = exc[ib] + tops[ib >> 10];
        } else rend = NE;
        for (int r = rbeg + tid; r < rend; r += 256) {
            unsigned int q = rec[r];
            float val = 1.0f / sqrtf((float)(q >> 13));
            atomicAdd(&Ach[q & 8191u], val);
        }
        __syncthreads();

        for (int c0 = 0; c0 < ROWS; c0 += 16) {
            for (int t = tid; t < 16 * 64; t += 256) {
                int jj = t >> 6, d4 = t & 63;
                int j = j0 + c0 + jj;
                float4 v = make_float4(0.f, 0.f, 0.f, 0.f);
                if (j < NN) {
                    float dv = dinv[j];
                    float4 u = ((const float4*)x)[(size_t)j * 64 + d4];
                    v.x = dv * u.x; v.y = dv * u.y; v.z = dv * u.z; v.w = dv * u.w;
                }
                ((float4*)xs[jj])[d4] = v;
            }
            __syncthreads();
#pragma unroll
            for (int jj = 0; jj < 16; ++jj) {
                const float* arow = &Ach[(c0 + jj) * 64 + gi * 8];
                float4 p0 = *(const float4*)arow;       // broadcast per half-wave
                float4 p1 = *(const float4*)(arow + 4);
                float xv[8];
#pragma unroll
                for (int k = 0; k < 8; ++k) xv[k] = xs[jj][di + 32 * k];  // bank-free
                float pg[8] = {p0.x, p0.y, p0.z, p0.w, p1.x, p1.y, p1.z, p1.w};
#pragma unroll
                for (int g = 0; g < 8; ++g)
#pragma unroll
                    for (int k = 0; k < 8; ++k)
                        acc[g][k] = fmaf(pg[g], xv[k], acc[g][k]);
            }
            __syncthreads();
        }
    }

    float* p = part + (size_t)blockIdx.x * (NG * DIMK);
#pragma unroll
    for (int g = 0; g < 8; ++g) {
        int gg = gi * 8 + g;
#pragma unroll
        for (int k = 0; k < 8; ++k)
            p[gg * DIMK + k * 32 + di] = acc[g][k];
    }
}

// Split-K reduce stage 1: 16 b-slices x 4096 float4 cols, coalesced.
__global__ __launch_bounds__(256) void k_reduce1(const float4* __restrict__ part,
        float4* __restrict__ p2, int nblk) {
    int id = blockIdx.x * 256 + threadIdx.x;   // 0..65535
    int c4 = id & 4095;
    int sl = id >> 12;
    int span = (nblk + NSL - 1) / NSL;
    int b0 = sl * span, b1 = min(b0 + span, nblk);
    float4 s = make_float4(0.f, 0.f, 0.f, 0.f);
    for (int b = b0; b < b1; ++b) {
        float4 v = part[(size_t)b * 4096 + c4];
        s.x += v.x; s.y += v.y; s.z += v.z; s.w += v.w;
    }
    p2[(size_t)sl * 4096 + c4] = s;
}

// Split-K reduce stage 2: fold 16 slices (1 MB, L2-resident).
__global__ void k_reduce2(const float4* __restrict__ p2, float4* __restrict__ S) {
    int c4 = blockIdx.x * 256 + threadIdx.x;   // 0..4095
    float4 s = make_float4(0.f, 0.f, 0.f, 0.f);
#pragma unroll
    for (int sl = 0; sl < NSL; ++sl) {
        float4 v = p2[(size_t)sl * 4096 + c4];
        s.x += v.x; s.y += v.y; s.z += v.z; s.w += v.w;
    }
    S[c4] = s;
}

__global__ void k_final(const float* __restrict__ S, const float* __restrict__ W,
                        const float* __restrict__ bias, const int* __restrict__ start,
                        float* __restrict__ out) {
    int idx = blockIdx.x * 256 + threadIdx.x;  // 0..2047
    int g = idx >> 5;
    int c = idx & 31;
    float sum = 0.f;
#pragma unroll 8
    for (int d = 0; d < DIMK; ++d)
        sum = fmaf(S[g * DIMK + d], W[d * NC + c], sum);
    float cn = (float)max(start[g + 1] - start[g], 1);
    out[idx] = sum / cn + bias[c];
}

extern "C" void kernel_launch(void* const* d_in, const int* in_sizes, int n_in,
                              void* d_out, int out_size, void* d_ws, size_t ws_size,
                              hipStream_t stream) {
    const float* x    = (const float*)d_in[0];
    const float* W    = (const float*)d_in[1];
    const float* bias = (const float*)d_in[2];
    const void*  ei   = d_in[3];
    const void*  batch= d_in[4];
    float* out = (float*)d_out;

    char* ws = (char*)d_ws;
    unsigned int* rec  = (unsigned int*)(ws + OFF_REC);
    unsigned int* degp = (unsigned int*)(ws + OFF_REC);   // overlay (dead before rec)
    unsigned int* degarr = (unsigned int*)(ws + OFF_DEGARR);
    float* dinv  = (float*)(ws + OFF_DINV);
    int*   cntp  = (int*)(ws + OFF_CNT);
    int*   exc   = (int*)(ws + OFF_EXC);
    int*   bsum  = (int*)(ws + OFF_BSUM);
    int*   tops  = (int*)(ws + OFF_TOPS);
    int*   start = (int*)(ws + OFF_START);
    int*   flag  = (int*)(ws + OFF_FLAG);
    float* S     = (float*)(ws + OFF_S);
    float* p2    = (float*)(ws + OFF_P2);
    float* part  = (float*)(ws + OFF_PART);

    int nblk = 64;   // fallback if workspace is tight
    if (ws_size >= OFF_PART + 391ull * NG * DIMK * 4) nblk = 391;

    k_detect      <<<1, 1, 0, stream>>>((const int*)ei, flag);
    k_deg_hist    <<<256, 256, 0, stream>>>(ei, degp, flag);
    k_deg_reduce  <<<98, 256, 0, stream>>>(degp, degarr, dinv);
    k_start       <<<391, 256, 0, stream>>>(batch, start, flag);
    k_bucket_count<<<NB1, 256, 0, stream>>>(ei, cntp, flag);
    k_scan_partial<<<NSCAN, 1024, 0, stream>>>(cntp, exc, bsum);
    k_scan_tops   <<<1, 64, 0, stream>>>(bsum, tops);
    k_place       <<<NB1, 256, 0, stream>>>(ei, batch, degarr, exc, tops, rec, flag);
    k_fused       <<<nblk, 256, 0, stream>>>(x, dinv, batch, rec, exc, tops, part, flag);
    k_reduce1     <<<256, 256, 0, stream>>>((const float4*)part, (float4*)p2, nblk);
    k_reduce2     <<<16, 256, 0, stream>>>((const float4*)p2, (float4*)S);
    k_final       <<<8, 256, 0, stream>>>(S, W, bias, start, out);
}